// Round 1
// baseline (72.014 us; speedup 1.0000x reference)
//
#include <hip/hip_runtime.h>

static constexpr int Bb = 4, Qq = 64, Nn = 4096, Kk = 512, Cc = 256, Tt = 32768;
static constexpr float kLog2e = 1.4426950408889634f;
static constexpr float kLn2 = 0.6931471805599453f;
static constexpr float kInvCount = 1.0f / 131072.0f;  // B * T

// ---------------------------------------------------------------------------
// Kernel 1: reconstruction loss.  One thread per (b, t) column, streaming
// online logsumexp over C=256 classes (coalesced: lanes cover consecutive t).
// ---------------------------------------------------------------------------
__global__ __launch_bounds__(256) void recon_kernel(const float* __restrict__ qp,
                                                    const int* __restrict__ tgt,
                                                    float* __restrict__ out) {
  const int col = blockIdx.x * 256 + threadIdx.x;   // 0 .. 131071
  const int b = col >> 15;                          // / T
  const int t = col & (Tt - 1);
  const int target = tgt[col];
  const float* base = qp + (size_t)b * Cc * Tt + t;

  float m = -INFINITY, s = 0.0f, vt = 0.0f;
#pragma unroll 8
  for (int c = 0; c < Cc; ++c) {
    float v = base[(size_t)c * Tt];
    vt = (c == target) ? v : vt;                    // capture qp[b, tgt, t]
    float u = v * kLog2e;                           // base-2 domain
    float mn = fmaxf(m, u);
    s = s * __builtin_amdgcn_exp2f(m - mn) + __builtin_amdgcn_exp2f(u - mn);
    m = mn;
  }
  float lse = (m + __builtin_amdgcn_logf(s)) * kLn2;  // natural logsumexp
  float contrib = lse - vt;                           // -log_softmax[target]

  // block reduce -> one atomic per block
#pragma unroll
  for (int off = 32; off > 0; off >>= 1) contrib += __shfl_down(contrib, off);
  __shared__ float wsum[4];
  if ((threadIdx.x & 63) == 0) wsum[threadIdx.x >> 6] = contrib;
  __syncthreads();
  if (threadIdx.x == 0)
    atomicAdd(out, (wsum[0] + wsum[1] + wsum[2] + wsum[3]) * kInvCount);
}

// ---------------------------------------------------------------------------
// Kernel 2: VQ term.  Block = 256 threads handles 64 columns (one b, 64 n).
// Register tile: thread = 4 cols x 8 codes; k processed in 4 chunks of 128.
// argmin over expanded-form score (emb2 - 2*cross); l2 recomputed directly.
// Mean over t of the transposed local conv collapses to weight W_n.
// ---------------------------------------------------------------------------
__global__ __launch_bounds__(256) void vq_kernel(const float* __restrict__ ze,
                                                 const float* __restrict__ emb,
                                                 const float* __restrict__ cw,
                                                 float* __restrict__ out) {
  __shared__ float zs[64 * 68];                 // [col][q], padded stride 68
  __shared__ float es[128 * 68];                // [k-chunk row][q]
  __shared__ float e2s[Kk];                     // ||emb_k||^2
  __shared__ unsigned long long red[64 * 16];   // per-col argmin reduction

  const int tid = threadIdx.x;
  const int b = blockIdx.x >> 6;                // 64 blocks per batch
  const int n0 = (blockIdx.x & 63) << 6;
  const float* zebase = ze + (size_t)b * Qq * Nn + n0;

  // stage ze tile (transposed: zs[n][q]), coalesced on n
  for (int idx = tid; idx < 64 * 64; idx += 256) {
    int q = idx >> 6, n = idx & 63;
    zs[n * 68 + q] = zebase[(size_t)q * Nn + n];
  }
  // precompute ||emb_k||^2
  for (int k = tid; k < Kk; k += 256) {
    const float4* row = (const float4*)(emb + (size_t)k * Qq);
    float acc = 0.f;
#pragma unroll
    for (int i = 0; i < 16; ++i) {
      float4 f = row[i];
      acc += f.x * f.x + f.y * f.y + f.z * f.z + f.w * f.w;
    }
    e2s[k] = acc;
  }

  const int ct = tid & 15;    // column group: cols [4ct, 4ct+4)
  const int kt = tid >> 4;    // code group:   rows [8kt, 8kt+8) of the chunk
  float best[4] = {INFINITY, INFINITY, INFINITY, INFINITY};
  int bestk[4] = {0, 0, 0, 0};

  for (int ch = 0; ch < 4; ++ch) {
    __syncthreads();          // also covers zs/e2s staging on first pass
    for (int idx = tid; idx < 128 * 64; idx += 256) {
      int kk = idx >> 6, q = idx & 63;
      es[kk * 68 + q] = emb[(size_t)(ch * 128 + kk) * Qq + q];
    }
    __syncthreads();

    float acc[4][8];
#pragma unroll
    for (int ci = 0; ci < 4; ++ci)
#pragma unroll
      for (int j = 0; j < 8; ++j) acc[ci][j] = 0.f;

    for (int qc = 0; qc < 16; ++qc) {
      float4 zv[4];
#pragma unroll
      for (int ci = 0; ci < 4; ++ci)
        zv[ci] = *(const float4*)&zs[(4 * ct + ci) * 68 + 4 * qc];
#pragma unroll
      for (int j = 0; j < 8; ++j) {
        float4 ev = *(const float4*)&es[(8 * kt + j) * 68 + 4 * qc];
#pragma unroll
        for (int ci = 0; ci < 4; ++ci)
          acc[ci][j] += zv[ci].x * ev.x + zv[ci].y * ev.y +
                        zv[ci].z * ev.z + zv[ci].w * ev.w;
      }
    }
#pragma unroll
    for (int j = 0; j < 8; ++j) {
      int k = ch * 128 + 8 * kt + j;
      float e2 = e2s[k];
#pragma unroll
      for (int ci = 0; ci < 4; ++ci) {
        float score = e2 - 2.0f * acc[ci][j];   // argmin score (ze2 dropped)
        if (score < best[ci]) { best[ci] = score; bestk[ci] = k; }
      }
    }
  }

  // pack (score,k) into sortable u64 so min() gives first-min tie-break
#pragma unroll
  for (int ci = 0; ci < 4; ++ci) {
    unsigned u = __float_as_uint(best[ci]);
    u = (u & 0x80000000u) ? ~u : (u | 0x80000000u);
    red[(4 * ct + ci) * 16 + kt] =
        ((unsigned long long)u << 32) | (unsigned)bestk[ci];
  }
  __syncthreads();

  if (tid < 64) {   // wave 0: one lane per column
    unsigned long long mn = red[tid * 16 + 0];
#pragma unroll
    for (int i = 1; i < 16; ++i) {
      unsigned long long v = red[tid * 16 + i];
      mn = (v < mn) ? v : mn;
    }
    int kb = (int)(unsigned)(mn & 0xffffffffull);

    // recompute l2 = sum_q (ze - emb[kb])^2 directly (matches reference)
    const float4* er = (const float4*)(emb + (size_t)kb * Qq);
    float l2 = 0.f;
#pragma unroll
    for (int i = 0; i < 16; ++i) {
      float4 e4 = er[i];
      float d0 = zs[tid * 68 + 4 * i + 0] - e4.x;
      float d1 = zs[tid * 68 + 4 * i + 1] - e4.y;
      float d2 = zs[tid * 68 + 4 * i + 2] - e4.z;
      float d3 = zs[tid * 68 + 4 * i + 3] - e4.w;
      l2 += d0 * d0 + d1 * d1 + d2 * d2 + d3 * d3;
    }

    // mean over t of conv_transpose == per-n weight; last n loses w[0] tap
    float wacc = 0.f;
#pragma unroll
    for (int i = 0; i < 9; ++i) wacc += cw[i];
    if (n0 + tid == Nn - 1) wacc -= cw[0];
    float val = 1.25f * l2 * wacc;   // (1 + GAMMA) * l2

#pragma unroll
    for (int off = 32; off > 0; off >>= 1) val += __shfl_down(val, off);
    if (tid == 0) atomicAdd(out, val * kInvCount);
  }
}

extern "C" void kernel_launch(void* const* d_in, const int* in_sizes, int n_in,
                              void* d_out, int out_size, void* d_ws, size_t ws_size,
                              hipStream_t stream) {
  const float* qp  = (const float*)d_in[0];   // (B, C, T) f32
  const int*   tgt = (const int*)d_in[1];     // (B, T) i32
  const float* ze  = (const float*)d_in[2];   // (B, Q, N) f32
  const float* emb = (const float*)d_in[3];   // (K, Q) f32
  const float* cw  = (const float*)d_in[4];   // (9,) f32
  float* out = (float*)d_out;                 // scalar f32

  hipMemsetAsync(out, 0, sizeof(float), stream);  // atomics accumulate into it
  vq_kernel<<<dim3(256), dim3(256), 0, stream>>>(ze, emb, cw, out);
  recon_kernel<<<dim3(512), dim3(256), 0, stream>>>(qp, tgt, out);
}